// Round 13
// baseline (207.386 us; speedup 1.0000x reference)
//
#include <hip/hip_runtime.h>
#include <hip/hip_bf16.h>
#include <cmath>
#include <cstdint>

// Problem dims (fixed by the reference)
#define BB 4
#define SS 2048
#define DD 1024
#define HH 16
#define MM (BB * SS)   // 8192 tokens

// softmax scale folded into Q weight columns: (1/sqrt(64)) * log2(e)
#define ATT_C 0.18033688011112042f

typedef __attribute__((ext_vector_type(8))) __bf16 bf16x8;
typedef __attribute__((ext_vector_type(4))) float f32x4;
typedef __attribute__((ext_vector_type(8))) float f32x8;
typedef __attribute__((ext_vector_type(8))) unsigned short u16x8;
typedef __attribute__((ext_vector_type(2))) unsigned int u32x2;
typedef __attribute__((ext_vector_type(4))) unsigned int u32x4;

typedef const __attribute__((address_space(3))) unsigned short* lds_cp;

__device__ __forceinline__ unsigned short f2bu(float f) {
  __hip_bfloat16 h = __float2bfloat16(f);
  return __builtin_bit_cast(unsigned short, h);
}

__device__ __forceinline__ f32x4 mfma16(bf16x8 a, bf16x8 b, f32x4 c) {
  return __builtin_amdgcn_mfma_f32_16x16x32_bf16(a, b, c, 0, 0, 0);
}

#define GLD16(gp, lp) __builtin_amdgcn_global_load_lds(                     \
    (const __attribute__((address_space(1))) void*)(gp),                    \
    (__attribute__((address_space(3))) void*)(lp), 16, 0, 0)

#define DSR128(dst, ptr, OFFLIT) \
  asm volatile("ds_read_b128 %0, %1 offset:" OFFLIT : "=v"(dst) : "v"(ptr))
#define LGKM(N) do { asm volatile("s_waitcnt lgkmcnt(" #N ")" ::: "memory"); \
                     __builtin_amdgcn_sched_barrier(0); } while (0)
#define VMCNT(N) do { asm volatile("s_waitcnt vmcnt(" #N ")" ::: "memory"); \
                      __builtin_amdgcn_sched_barrier(0); } while (0)

// ---------------- prep: fp32 -> bf16 cast (vectorized) ----------------
__global__ __launch_bounds__(256) void k_cast_bf16(const float* __restrict__ in,
                                                   unsigned short* __restrict__ out,
                                                   int n) {
  int i = (blockIdx.x * 256 + threadIdx.x) * 8;
  if (i >= n) return;
  f32x8 v = *(const f32x8*)(in + i);
  u16x8 o;
#pragma unroll
  for (int j = 0; j < 8; ++j) o[j] = f2bu(v[j]);
  *(u16x8*)(out + i) = o;
}

// ---------------- prep: transpose + cast  in[R][C] f32 -> out[C][R] bf16 ----------------
// output rows < scale_end get multiplied by scale (folds softmax scale into Q weights)
__global__ __launch_bounds__(256) void k_transpose_bf16(const float* __restrict__ in,
                                                        unsigned short* __restrict__ out,
                                                        int R, int C,
                                                        float scale, int scale_end) {
  __shared__ float tile[32][33];
  const int c0 = blockIdx.x * 32, r0 = blockIdx.y * 32;
  const int tx = threadIdx.x & 31, ty = threadIdx.x >> 5;  // ty 0..7
#pragma unroll
  for (int i = ty; i < 32; i += 8)
    tile[i][tx] = in[(size_t)(r0 + i) * C + c0 + tx];
  __syncthreads();
#pragma unroll
  for (int i = ty; i < 32; i += 8) {
    float v = tile[tx][i];
    if (c0 + i < scale_end) v *= scale;
    out[(size_t)(c0 + i) * R + r0 + tx] = f2bu(v);
  }
}

// ---------------- bf16 GEMM: 128x128 tile, 2-deep counted pipeline (r9 form) ----------
// C[M][N] = A[M][K] * Bt[N][K]^T + bias[N]  (bias cols < bias_scale_end scaled by ATT_C)
// LDS [row][64k], 16B-chunk XOR swizzle ch^(row&7), staged via pre-swizzled source.
template <int OUT_F32>
__global__ __launch_bounds__(256) void k_gemm_bt(const unsigned short* __restrict__ A,
                                                 const unsigned short* __restrict__ Bt,
                                                 const float* __restrict__ bias,
                                                 void* __restrict__ Cout,
                                                 int M, int N, int K, int bias_scale_end) {
  __shared__ __attribute__((aligned(16))) unsigned short lA[2][128 * 64];
  __shared__ __attribute__((aligned(16))) unsigned short lB[2][128 * 64];
  const int tid = threadIdx.x;
  const int wave = tid >> 6, lane = tid & 63;
  const int g = lane >> 4, c = lane & 15;
  const int wr = wave >> 1, wc = wave & 1;
  const int m0 = blockIdx.y * 128, n0 = blockIdx.x * 128;
  const int srow = lane >> 3;                  // 0..7 row within 8-row group
  const int sch  = ((lane & 7) ^ srow) * 8;    // XOR-pre-swizzled source k-chunk

  f32x4 acc[4][4] = {};
  const int nkt = K >> 6;

#define GSTAGE(buf, kt) do {                                                     \
    const int k0s = (kt) * 64;                                                   \
    _Pragma("unroll")                                                            \
    for (int i_ = 0; i_ < 4; ++i_) {                                             \
      const int chunk = i_ * 4 + wave;                                           \
      GLD16(A + (size_t)(m0 + chunk * 8 + srow) * K + k0s + sch,                 \
            &lA[buf][0] + chunk * 512);                                          \
      GLD16(Bt + (size_t)(n0 + chunk * 8 + srow) * K + k0s + sch,                \
            &lB[buf][0] + chunk * 512);                                          \
    }                                                                            \
  } while (0)

  GSTAGE(0, 0);
  GSTAGE(1, 1);
  VMCNT(8);  // tile 0 landed (tile 1's 8 loads still in flight)
  __syncthreads();

  int p = 0;
  for (int kt = 0; kt < nkt; ++kt) {
    const int x7 = c & 7;
    const lds_cp a0 = (lds_cp)&lA[p][0] + (wr * 64 + c) * 64 + (g ^ x7) * 8;
    const lds_cp b0 = (lds_cp)&lB[p][0] + (wc * 64 + c) * 64 + (g ^ x7) * 8;
    const lds_cp a1 = (lds_cp)&lA[p][0] + (wr * 64 + c) * 64 + ((g ^ x7) ^ 4) * 8;
    const lds_cp b1 = (lds_cp)&lB[p][0] + (wc * 64 + c) * 64 + ((g ^ x7) ^ 4) * 8;
    u32x4 af0[4], bf0[4], af1[4], bf1[4];
    DSR128(af0[0], a0, "0");    DSR128(af0[1], a0, "2048");
    DSR128(af0[2], a0, "4096"); DSR128(af0[3], a0, "6144");
    DSR128(bf0[0], b0, "0");    DSR128(bf0[1], b0, "2048");
    DSR128(bf0[2], b0, "4096"); DSR128(bf0[3], b0, "6144");
    DSR128(af1[0], a1, "0");    DSR128(af1[1], a1, "2048");
    DSR128(af1[2], a1, "4096"); DSR128(af1[3], a1, "6144");
    DSR128(bf1[0], b1, "0");    DSR128(bf1[1], b1, "2048");
    DSR128(bf1[2], b1, "4096"); DSR128(bf1[3], b1, "6144");

    LGKM(8);  // kk0 frags ready (kk1 reads in flight)
    __builtin_amdgcn_s_setprio(1);
#pragma unroll
    for (int mi = 0; mi < 4; ++mi)
#pragma unroll
      for (int ni = 0; ni < 4; ++ni)
        acc[mi][ni] = mfma16(__builtin_bit_cast(bf16x8, af0[mi]),
                             __builtin_bit_cast(bf16x8, bf0[ni]), acc[mi][ni]);
    __builtin_amdgcn_s_setprio(0);

    LGKM(0);          // all reads from buf p done
    __syncthreads();  // every wave consumed buf p -> safe to overwrite
    if (kt + 2 < nkt) GSTAGE(p, kt + 2);

    __builtin_amdgcn_s_setprio(1);
#pragma unroll
    for (int mi = 0; mi < 4; ++mi)
#pragma unroll
      for (int ni = 0; ni < 4; ++ni)
        acc[mi][ni] = mfma16(__builtin_bit_cast(bf16x8, af1[mi]),
                             __builtin_bit_cast(bf16x8, bf1[ni]), acc[mi][ni]);
    __builtin_amdgcn_s_setprio(0);

    if (kt + 2 < nkt) { VMCNT(8); } else { VMCNT(0); }  // tile kt+1 landed
    __syncthreads();
    p ^= 1;
  }
#undef GSTAGE

#pragma unroll
  for (int mi = 0; mi < 4; ++mi)
#pragma unroll
    for (int ni = 0; ni < 4; ++ni) {
      const int col = n0 + wc * 64 + ni * 16 + c;
      float bv = bias[col];
      if (col < bias_scale_end) bv *= ATT_C;
#pragma unroll
      for (int r = 0; r < 4; ++r) {
        const int row = m0 + wr * 64 + mi * 16 + g * 4 + r;
        const float v = acc[mi][ni][r] + bv;
        if (OUT_F32)
          ((float*)Cout)[(size_t)row * N + col] = v;
        else
          ((unsigned short*)Cout)[(size_t)row * N + col] = f2bu(v);
      }
    }
}

// ---------------- causal flash attention (swapped QK^T, tr-read PV) ----------------
// qkv: [B*S][3072] bf16 (Q pre-scaled by ATT_C, K at 1024, V at 2048; head h at h*64)
// y:   [B*S][1024] bf16
// r13 = r9 with KVBLK=128: each staged buffer holds 128 keys (16KB K + 16KB V), and
// compute runs TWICE per buffer (sub-tiles of 64 keys) -> drains/barriers per block
// drop 34 -> 17 while per-key staging/LDS/register structure is byte-identical to r9.
// Block: 4 waves x 32 Q rows (m=2) = 128-row q-tile; TWO q-tiles (15-p, p) per block
// -> uniform 17 tile-steps. Grid 512, XCD-binding decode (bh%8 == xcd -> per-XCD
// L2-resident K/V, 8 bh x 512KB = 4MB per XCD L2). dbuf LDS = 64KB -> 2 blocks/CU.
// K LDS: row-major [128 keys][64 hd], 16B-chunk XOR swizzle ch^(row&7); staged coalesced.
// V LDS: tr-subtiles ordered (k4*4+dc)*128B (coalesced staging); tr-read base
//   (lane>>4)*512B + (lane&15)*8B. Row-sums of P via ones-MFMA.
__global__ __launch_bounds__(256) void k_attn(const unsigned short* __restrict__ qkv,
                                              unsigned short* __restrict__ y) {
  __shared__ __attribute__((aligned(16))) unsigned short lK[2][8192];
  __shared__ __attribute__((aligned(16))) unsigned short lV[2][8192];

  const int tid = threadIdx.x, wave = tid >> 6, lane = tid & 63;
  const int g = lane >> 4, c = lane & 15;
  const int id = (int)blockIdx.x;
  const int xcd = id & 7, slot = id >> 3;
  const int bh = xcd + 8 * (slot & 7);   // bh%8 == xcd -> per-XCD K/V residency
  const int pr = slot >> 3;              // 0..7 pair index
  const int b = bh >> 4, hc = bh & 15;
  const size_t rb = (size_t)b * SS;

  const int kRow = lane >> 3;                                  // 0..7 row within group
  const int kCh  = ((lane & 7) ^ kRow) * 8;                    // XOR-swizzled dim chunk
  const int vRow = 4 * ((lane >> 5) & 1) + ((lane >> 1) & 3);  // 0..7 key within group
  const int vDim = 16 * ((lane >> 3) & 3) + (lane & 1) * 8;    // dim offset

  // stage 128 keys: K rows wave*32..+31 (4 GLD16), V keys wave*32..+31 (4 GLD16)
#define STAGE(buf, kb) do {                                                        \
    const int k0s = (kb) * 128;                                                    \
    const int g32 = wave * 32;                                                     \
    unsigned short* kb_ = &lK[buf][0];                                             \
    unsigned short* vb_ = &lV[buf][0];                                             \
    _Pragma("unroll")                                                              \
    for (int j_ = 0; j_ < 4; ++j_)                                                 \
      GLD16(qkv + (rb + k0s + g32 + j_ * 8 + kRow) * 3072 + 1024 + hc * 64 + kCh,  \
            kb_ + (g32 + j_ * 8) * 64);                                            \
    _Pragma("unroll")                                                              \
    for (int j_ = 0; j_ < 4; ++j_)                                                 \
      GLD16(qkv + (rb + k0s + g32 + j_ * 8 + vRow) * 3072 + 2048 + hc * 64 + vDim, \
            vb_ + (g32 + j_ * 8) * 64);                                            \
  } while (0)

#define TRRD(dst, OFFLIT) \
  asm volatile("ds_read_b64_tr_b16 %0, %1 offset:" OFFLIT : "=v"(dst) : "v"(vp))

  bf16x8 onesf;
  {
    u16x8 t;
#pragma unroll
    for (int j = 0; j < 8; ++j) t[j] = 0x3F80;  // bf16 1.0
    onesf = __builtin_bit_cast(bf16x8, t);
  }

  auto run_qtile = [&](int qt) {
    const int qw = qt * 128 + wave * 32;

    bf16x8 qf[2][2];
#pragma unroll
    for (int m = 0; m < 2; ++m)
#pragma unroll
      for (int kh = 0; kh < 2; ++kh)
        qf[m][kh] = *(const bf16x8*)(qkv + (rb + qw + m * 16 + c) * 3072 + hc * 64 + kh * 32 + g * 8);

    float mrun[2] = {-INFINITY, -INFINITY};
    f32x4 lsum[2] = {};
    f32x4 o[2][4] = {};
    const int nkb = qt + 1;  // 128-key tiles

    // one 64-key sub-tile: sub in {0,1}
    auto compute = [&](int buf, int kb, int sub) {
      const int k0 = kb * 128 + sub * 64;
      if (k0 > qw + 31) return;  // fully masked for this wave (wave-uniform)

      const lds_cp kbase = (lds_cp)&lK[buf][0] + sub * 4096;
      const lds_cp kp0 = kbase + c * 64 + ((g ^ (c & 7))) * 8;
      const lds_cp kp1 = kbase + c * 64 + (((4 + g) ^ (c & 7))) * 8;
      u32x4 kr[8];
      DSR128(kr[0], kp0, "0");    DSR128(kr[1], kp0, "2048");
      DSR128(kr[2], kp0, "4096"); DSR128(kr[3], kp0, "6144");
      DSR128(kr[4], kp1, "0");    DSR128(kr[5], kp1, "2048");
      DSR128(kr[6], kp1, "4096"); DSR128(kr[7], kp1, "6144");
      const lds_cp vp = (lds_cp)&lV[buf][0] + sub * 4096 + (lane >> 4) * 256 + (lane & 15) * 4;
      u32x2 t0[8];
      TRRD(t0[0], "0");   TRRD(t0[1], "2048");
      TRRD(t0[2], "128"); TRRD(t0[3], "2176");
      TRRD(t0[4], "256"); TRRD(t0[5], "2304");
      TRRD(t0[6], "384"); TRRD(t0[7], "2432");
      LGKM(8);  // kr ready (t0 still in flight)

      f32x4 s[2][4];
      __builtin_amdgcn_s_setprio(1);
#pragma unroll
      for (int kf = 0; kf < 4; ++kf) {
        const bf16x8 ka = __builtin_bit_cast(bf16x8, kr[kf]);
        const bf16x8 kb2 = __builtin_bit_cast(bf16x8, kr[4 + kf]);
#pragma unroll
        for (int m = 0; m < 2; ++m) {
          f32x4 a = {};
          a = mfma16(ka, qf[m][0], a);
          a = mfma16(kb2, qf[m][1], a);
          s[m][kf] = a;
        }
      }
      __builtin_amdgcn_s_setprio(0);

      u32x2 t1[8];
      TRRD(t1[0], "4096"); TRRD(t1[1], "6144");
      TRRD(t1[2], "4224"); TRRD(t1[3], "6272");
      TRRD(t1[4], "4352"); TRRD(t1[5], "6400");
      TRRD(t1[6], "4480"); TRRD(t1[7], "6528");

#pragma unroll
      for (int m = 0; m < 2; ++m)
#pragma unroll
        for (int kf = 0; kf < 4; ++kf)
          if (k0 + kf * 16 + 15 > qw + m * 16) {
#pragma unroll
            for (int r = 0; r < 4; ++r)
              if (k0 + kf * 16 + 4 * g + r > qw + m * 16 + c) s[m][kf][r] = -INFINITY;
          }

#pragma unroll
      for (int m = 0; m < 2; ++m) {
        float a0 = fmaxf(fmaxf(s[m][0][0], s[m][0][1]), s[m][0][2]);
        float a1 = fmaxf(fmaxf(s[m][0][3], s[m][1][0]), s[m][1][1]);
        float a2 = fmaxf(fmaxf(s[m][1][2], s[m][1][3]), s[m][2][0]);
        float a3 = fmaxf(fmaxf(s[m][2][1], s[m][2][2]), s[m][2][3]);
        float a4 = fmaxf(fmaxf(s[m][3][0], s[m][3][1]), s[m][3][2]);
        float b0 = fmaxf(fmaxf(a0, a1), a2);
        float b1 = fmaxf(fmaxf(a3, a4), s[m][3][3]);
        float tmax = fmaxf(b0, b1);
        tmax = fmaxf(tmax, __shfl_xor(tmax, 16));
        tmax = fmaxf(tmax, __shfl_xor(tmax, 32));
        const float mold = mrun[m];
        float mt;
        if (__all(tmax - mold <= 8.f)) {
          mt = mold;
        } else {
          mt = fmaxf(mold, tmax);
          const float alpha = __builtin_amdgcn_exp2f(mold - mt);
          mrun[m] = mt;
#pragma unroll
          for (int r = 0; r < 4; ++r) {
            const float ao = __shfl(alpha, (lane & 48) + ((lane & 48) >> 2) + r);
            lsum[m][r] *= ao;
#pragma unroll
            for (int dc = 0; dc < 4; ++dc) o[m][dc][r] *= ao;
          }
        }
#pragma unroll
        for (int kf = 0; kf < 4; ++kf)
#pragma unroll
          for (int r = 0; r < 4; ++r)
            s[m][kf][r] = __builtin_amdgcn_exp2f(s[m][kf][r] - mt);
      }

      bf16x8 pa[2][2];
#pragma unroll
      for (int m = 0; m < 2; ++m)
#pragma unroll
        for (int kh = 0; kh < 2; ++kh) {
          u16x8 t;
#pragma unroll
          for (int j = 0; j < 4; ++j) {
            t[j]     = f2bu(s[m][2 * kh][j]);
            t[4 + j] = f2bu(s[m][2 * kh + 1][j]);
          }
          pa[m][kh] = __builtin_bit_cast(bf16x8, t);
        }

      LGKM(8);  // t0 ready (t1 younger, still in flight)
      __builtin_amdgcn_s_setprio(1);
#pragma unroll
      for (int m = 0; m < 2; ++m) {
        lsum[m] = mfma16(pa[m][0], onesf, lsum[m]);
        lsum[m] = mfma16(pa[m][1], onesf, lsum[m]);
      }
#pragma unroll
      for (int dc = 0; dc < 4; ++dc) {
        u32x4 vv = {t0[2 * dc][0], t0[2 * dc][1], t0[2 * dc + 1][0], t0[2 * dc + 1][1]};
        const bf16x8 vf = __builtin_bit_cast(bf16x8, vv);
#pragma unroll
        for (int m = 0; m < 2; ++m) o[m][dc] = mfma16(pa[m][0], vf, o[m][dc]);
      }
      __builtin_amdgcn_s_setprio(0);

      LGKM(0);  // t1 ready
      __builtin_amdgcn_s_setprio(1);
#pragma unroll
      for (int dc = 0; dc < 4; ++dc) {
        u32x4 vv = {t1[2 * dc][0], t1[2 * dc][1], t1[2 * dc + 1][0], t1[2 * dc + 1][1]};
        const bf16x8 vf = __builtin_bit_cast(bf16x8, vv);
#pragma unroll
        for (int m = 0; m < 2; ++m) o[m][dc] = mfma16(pa[m][1], vf, o[m][dc]);
      }
      __builtin_amdgcn_s_setprio(0);
    };

    __syncthreads();  // LDS handoff from previous q-tile
    STAGE(0, 0);
    asm volatile("s_waitcnt vmcnt(0)" ::: "memory");
    __syncthreads();
    int cur = 0;
    for (int kb = 0; kb < nkb - 1; ++kb) {
      STAGE(cur ^ 1, kb + 1);
      compute(cur, kb, 0);
      compute(cur, kb, 1);
      asm volatile("s_waitcnt vmcnt(0)" ::: "memory");
      __syncthreads();
      cur ^= 1;
    }
    compute(cur, nkb - 1, 0);
    compute(cur, nkb - 1, 1);

    // epilogue: normalize and store (lsum already in o's layout — no shfl)
#pragma unroll
    for (int m = 0; m < 2; ++m)
#pragma unroll
      for (int r = 0; r < 4; ++r) {
        const float inv = __builtin_amdgcn_rcpf(lsum[m][r]);
        const int q = qw + m * 16 + 4 * g + r;
#pragma unroll
        for (int dc = 0; dc < 4; ++dc)
          y[(rb + q) * 1024 + hc * 64 + dc * 16 + c] = f2bu(o[m][dc][r] * inv);
      }
  };

  // paired q-tiles: (15-p) then (p) -> uniform 17 tile-steps per block
  run_qtile(15 - pr);
  run_qtile(pr);
#undef STAGE
#undef TRRD
}

// ---------------- launch ----------------
extern "C" void kernel_launch(void* const* d_in, const int* in_sizes, int n_in,
                              void* d_out, int out_size, void* d_ws, size_t ws_size,
                              hipStream_t stream) {
  (void)in_sizes; (void)n_in; (void)out_size; (void)ws_size;
  const float* x     = (const float*)d_in[0];
  const float* w_qkv = (const float*)d_in[1];
  const float* b_qkv = (const float*)d_in[2];
  const float* w_out = (const float*)d_in[3];
  const float* b_out = (const float*)d_in[4];
  float* out = (float*)d_out;

  char* ws = (char*)d_ws;
  unsigned short* x_bf  = (unsigned short*)(ws);                        // 16 MB (reused for y)
  unsigned short* wqkvT = (unsigned short*)(ws + (size_t)16 * 1048576); // 6 MB
  unsigned short* woutT = (unsigned short*)(ws + (size_t)22 * 1048576); // 2 MB
  unsigned short* qkv   = (unsigned short*)(ws + (size_t)24 * 1048576); // 48 MB -> total 72 MB

  // prep (Q weight columns pre-scaled by ATT_C)
  k_cast_bf16<<<dim3((MM * DD) / (256 * 8)), 256, 0, stream>>>(x, x_bf, MM * DD);
  k_transpose_bf16<<<dim3(3 * DD / 32, DD / 32), 256, 0, stream>>>(w_qkv, wqkvT, DD, 3 * DD,
                                                                   ATT_C, DD);
  k_transpose_bf16<<<dim3(DD / 32, DD / 32), 256, 0, stream>>>(w_out, woutT, DD, DD, 1.f, 0);

  // QKV projection: [8192,3072] bf16 (r9's proven 128² pipeline)
  k_gemm_bt<0><<<dim3(3 * DD / 128, MM / 128), 256, 0, stream>>>(
      x_bf, wqkvT, b_qkv, qkv, MM, 3 * DD, DD, DD);

  // causal attention -> y (bf16, reuses x_bf region); grid 512, XCD-binding decode
  k_attn<<<dim3(512), 256, 0, stream>>>(qkv, x_bf);

  // output projection: fp32 out
  k_gemm_bt<1><<<dim3(DD / 128, MM / 128), 256, 0, stream>>>(
      x_bf, woutT, b_out, out, MM, DD, DD, 0);
}

// Round 14
// 177.409 us; speedup vs baseline: 1.1690x; 1.1690x over previous
//
#include <hip/hip_runtime.h>
#include <hip/hip_bf16.h>
#include <cmath>
#include <cstdint>

// Problem dims (fixed by the reference)
#define BB 4
#define SS 2048
#define DD 1024
#define HH 16
#define MM (BB * SS)   // 8192 tokens

// softmax scale folded into Q weight columns: (1/sqrt(64)) * log2(e)
#define ATT_C 0.18033688011112042f

typedef __attribute__((ext_vector_type(8))) __bf16 bf16x8;
typedef __attribute__((ext_vector_type(4))) float f32x4;
typedef __attribute__((ext_vector_type(8))) float f32x8;
typedef __attribute__((ext_vector_type(8))) unsigned short u16x8;
typedef __attribute__((ext_vector_type(2))) unsigned int u32x2;
typedef __attribute__((ext_vector_type(4))) unsigned int u32x4;

typedef const __attribute__((address_space(3))) unsigned short* lds_cp;

__device__ __forceinline__ unsigned short f2bu(float f) {
  __hip_bfloat16 h = __float2bfloat16(f);
  return __builtin_bit_cast(unsigned short, h);
}

__device__ __forceinline__ f32x4 mfma16(bf16x8 a, bf16x8 b, f32x4 c) {
  return __builtin_amdgcn_mfma_f32_16x16x32_bf16(a, b, c, 0, 0, 0);
}

#define GLD16(gp, lp) __builtin_amdgcn_global_load_lds(                     \
    (const __attribute__((address_space(1))) void*)(gp),                    \
    (__attribute__((address_space(3))) void*)(lp), 16, 0, 0)

#define DSR128(dst, ptr, OFFLIT) \
  asm volatile("ds_read_b128 %0, %1 offset:" OFFLIT : "=v"(dst) : "v"(ptr))
#define LGKM(N) do { asm volatile("s_waitcnt lgkmcnt(" #N ")" ::: "memory"); \
                     __builtin_amdgcn_sched_barrier(0); } while (0)
#define VMCNT(N) do { asm volatile("s_waitcnt vmcnt(" #N ")" ::: "memory"); \
                      __builtin_amdgcn_sched_barrier(0); } while (0)
#define RBAR() __builtin_amdgcn_s_barrier()

// ---------------- prep: fp32 -> bf16 cast (vectorized) ----------------
__global__ __launch_bounds__(256) void k_cast_bf16(const float* __restrict__ in,
                                                   unsigned short* __restrict__ out,
                                                   int n) {
  int i = (blockIdx.x * 256 + threadIdx.x) * 8;
  if (i >= n) return;
  f32x8 v = *(const f32x8*)(in + i);
  u16x8 o;
#pragma unroll
  for (int j = 0; j < 8; ++j) o[j] = f2bu(v[j]);
  *(u16x8*)(out + i) = o;
}

// ---------------- prep: transpose + cast  in[R][C] f32 -> out[C][R] bf16 ----------------
__global__ __launch_bounds__(256) void k_transpose_bf16(const float* __restrict__ in,
                                                        unsigned short* __restrict__ out,
                                                        int R, int C,
                                                        float scale, int scale_end) {
  __shared__ float tile[32][33];
  const int c0 = blockIdx.x * 32, r0 = blockIdx.y * 32;
  const int tx = threadIdx.x & 31, ty = threadIdx.x >> 5;  // ty 0..7
#pragma unroll
  for (int i = ty; i < 32; i += 8)
    tile[i][tx] = in[(size_t)(r0 + i) * C + c0 + tx];
  __syncthreads();
#pragma unroll
  for (int i = ty; i < 32; i += 8) {
    float v = tile[tx][i];
    if (c0 + i < scale_end) v *= scale;
    out[(size_t)(c0 + i) * R + r0 + tx] = f2bu(v);
  }
}

// ---------------- GEMM1: 256x256 tile, 8-phase pipeline (m201 template port) ----------
// C[M][N] = A[M][K]*Bt[N][K]^T + bias (cols < bse scaled by ATT_C); bf16 out.
// 512 thr = 8 waves (2M x 4N); wave tile 128x64 -> acc[8][4]. LDS 128KB:
// lA[2dbuf][2 mhalf][128x64], lB[2dbuf][2 nhalf][128x64], chunk-XOR swizzle ch^(row&7)
// (pre-swizzled global source, swizzled read — both-sides). Every half-tile = exactly
// 2 GLD16/thread (uniform -> per-wave vmcnt counts consistent).
// Iteration = 2 K-tiles (d0 even, d1 odd). 8 phases, each:
//   {stage 1 half-tile || 4-8 ds_read_b128} -> s_barrier -> lgkm(0) -> 16 MFMA -> s_barrier
// Stage plan/iter it: ph0 B-d1h1<-t1, ph1 A-d1h0<-t1, ph2 A-d1h1<-t1, ph3 B-d0h0<-t2,
//   ph4 B-d0h1<-t2, ph5 A-d0h0<-t2, ph6 A-d0h1<-t2, ph7 B-d1h0<-t3  (t1=2it+1 etc.)
// Each restage is >=1 barrier after its region's last ds_read (verified per phase).
// VMCNT(2) before the CLOSING barrier of ph3 (d1 landed) and ph7 (d0 landed):
// per-wave wait + barrier => all waves' loads landed chip-wide before next reads.
__global__ __launch_bounds__(512) void k_gemm8p(const unsigned short* __restrict__ A,
                                                const unsigned short* __restrict__ Bt,
                                                const float* __restrict__ bias,
                                                unsigned short* __restrict__ C,
                                                int M, int N, int K, int bse) {
  __shared__ __attribute__((aligned(16))) unsigned short lA[2][2][8192];
  __shared__ __attribute__((aligned(16))) unsigned short lB[2][2][8192];
  const int tid = threadIdx.x;
  const int wave = tid >> 6, lane = tid & 63;
  const int g = lane >> 4, c = lane & 15;
  const int wr = wave >> 2, wc = wave & 3;          // 2M x 4N wave grid
  const int m0 = blockIdx.y * 256, n0 = blockIdx.x * 256;
  const int srow = lane >> 3;                       // 0..7 row within 8-row group
  const int sch  = ((lane & 7) ^ srow) * 8;         // XOR-pre-swizzled source k-chunk
  const int x7 = c & 7;

  f32x4 acc[8][4] = {};
  const int nkt = K >> 6;  // 16 (even)

  // stage one half-tile (128 rows x 64 k): 2 GLD16/thread (rowgroups wave, wave+8)
#define STH(half_base, Mat, row0, kt) do {                                        \
    GLD16(Mat + (size_t)((row0) + wave * 8 + srow) * K + (kt) * 64 + sch,         \
          (half_base) + wave * 512);                                              \
    GLD16(Mat + (size_t)((row0) + 64 + wave * 8 + srow) * K + (kt) * 64 + sch,    \
          (half_base) + 4096 + wave * 512);                                       \
  } while (0)
#define STA(d, h, kt) STH(&lA[d][h][0], A,  m0 + (h) * 128, kt)
#define STB(d, h, kt) STH(&lB[d][h][0], Bt, n0 + (h) * 128, kt)

  // read base pointers (compile-time-named, no runtime indexing)
  const lds_cp pA00 = (lds_cp)&lA[0][wr][0] + c * 64 + ((g ^ x7)) * 8;
  const lds_cp pA01 = (lds_cp)&lA[0][wr][0] + c * 64 + ((g ^ x7) ^ 4) * 8;
  const lds_cp pA10 = (lds_cp)&lA[1][wr][0] + c * 64 + ((g ^ x7)) * 8;
  const lds_cp pA11 = (lds_cp)&lA[1][wr][0] + c * 64 + ((g ^ x7) ^ 4) * 8;
  const lds_cp pB00 = (lds_cp)&lB[0][wc >> 1][0] + ((wc & 1) * 64 + c) * 64 + ((g ^ x7)) * 8;
  const lds_cp pB01 = (lds_cp)&lB[0][wc >> 1][0] + ((wc & 1) * 64 + c) * 64 + ((g ^ x7) ^ 4) * 8;
  const lds_cp pB10 = (lds_cp)&lB[1][wc >> 1][0] + ((wc & 1) * 64 + c) * 64 + ((g ^ x7)) * 8;
  const lds_cp pB11 = (lds_cp)&lB[1][wc >> 1][0] + ((wc & 1) * 64 + c) * 64 + ((g ^ x7) ^ 4) * 8;

  u32x4 af[4], bfr[4];

#define RDA0(P) do { DSR128(af[0], P, "0");    DSR128(af[1], P, "2048");   \
                     DSR128(af[2], P, "4096"); DSR128(af[3], P, "6144"); } while (0)
#define RDA1(P) do { DSR128(af[0], P, "8192");  DSR128(af[1], P, "10240"); \
                     DSR128(af[2], P, "12288"); DSR128(af[3], P, "14336"); } while (0)
#define RDB(P)  do { DSR128(bfr[0], P, "0");    DSR128(bfr[1], P, "2048"); \
                     DSR128(bfr[2], P, "4096"); DSR128(bfr[3], P, "6144"); } while (0)
#define MF16(mg) do { __builtin_amdgcn_s_setprio(1);                               \
    _Pragma("unroll") for (int mi = 0; mi < 4; ++mi)                               \
    _Pragma("unroll") for (int ni = 0; ni < 4; ++ni)                               \
      acc[(mg) * 4 + mi][ni] = mfma16(__builtin_bit_cast(bf16x8, af[mi]),          \
                                      __builtin_bit_cast(bf16x8, bfr[ni]),         \
                                      acc[(mg) * 4 + mi][ni]);                     \
    __builtin_amdgcn_s_setprio(0); } while (0)

  // prologue: d0 <- tile0 (4 halves), d1 B-h0 <- tile1 (the "ph7" slot)
  STA(0, 0, 0); STA(0, 1, 0); STB(0, 0, 0); STB(0, 1, 0);
  STB(1, 0, 1);
  VMCNT(2);
  RBAR();

  for (int it = 0; it < (nkt >> 1); ++it) {
    const int t1 = 2 * it + 1, t2 = 2 * it + 2, t3 = 2 * it + 3;
    // ph0: d0/mg0/kk0 (+B kk0)
    STB(1, 1, t1);
    RDA0(pA00); RDB(pB00);
    RBAR(); LGKM(0); MF16(0); RBAR();
    // ph1: d0/mg1/kk0
    STA(1, 0, t1);
    RDA1(pA00);
    RBAR(); LGKM(0); MF16(1); RBAR();
    // ph2: d0/mg0/kk1 (+B kk1)
    STA(1, 1, t1);
    RDA0(pA01); RDB(pB01);
    RBAR(); LGKM(0); MF16(0); RBAR();
    // ph3: d0/mg1/kk1 ; boundary wait: d1 (tile t1) must be landed for ph4-7
    if (t2 < nkt) STB(0, 0, t2);
    RDA1(pA01);
    RBAR(); LGKM(0); MF16(1);
    if (t2 < nkt) { VMCNT(2); } else { VMCNT(0); }
    RBAR();
    // ph4: d1/mg0/kk0 (+B kk0)
    if (t2 < nkt) STB(0, 1, t2);
    RDA0(pA10); RDB(pB10);
    RBAR(); LGKM(0); MF16(0); RBAR();
    // ph5: d1/mg1/kk0
    if (t2 < nkt) STA(0, 0, t2);
    RDA1(pA10);
    RBAR(); LGKM(0); MF16(1); RBAR();
    // ph6: d1/mg0/kk1 (+B kk1)
    if (t2 < nkt) STA(0, 1, t2);
    RDA0(pA11); RDB(pB11);
    RBAR(); LGKM(0); MF16(0); RBAR();
    // ph7: d1/mg1/kk1 ; boundary wait: d0 (tile t2) landed for next ph0-3
    if (t3 < nkt) STB(1, 0, t3);
    RDA1(pA11);
    RBAR(); LGKM(0); MF16(1);
    VMCNT(2);
    RBAR();
  }
#undef STH
#undef STA
#undef STB
#undef RDA0
#undef RDA1
#undef RDB
#undef MF16

  // epilogue: bias + bf16 store
#pragma unroll
  for (int mi = 0; mi < 8; ++mi)
#pragma unroll
    for (int ni = 0; ni < 4; ++ni) {
      const int col = n0 + wc * 64 + ni * 16 + c;
      float bv = bias[col];
      if (col < bse) bv *= ATT_C;
#pragma unroll
      for (int r = 0; r < 4; ++r) {
        const int row = m0 + wr * 128 + mi * 16 + g * 4 + r;
        C[(size_t)row * N + col] = f2bu(acc[mi][ni][r] + bv);
      }
    }
  (void)M;
}

// ---------------- bf16 GEMM: 128x128 tile, 2-deep counted pipeline (r9 form) ----------
template <int OUT_F32>
__global__ __launch_bounds__(256) void k_gemm_bt(const unsigned short* __restrict__ A,
                                                 const unsigned short* __restrict__ Bt,
                                                 const float* __restrict__ bias,
                                                 void* __restrict__ Cout,
                                                 int M, int N, int K, int bias_scale_end) {
  __shared__ __attribute__((aligned(16))) unsigned short lA[2][128 * 64];
  __shared__ __attribute__((aligned(16))) unsigned short lB[2][128 * 64];
  const int tid = threadIdx.x;
  const int wave = tid >> 6, lane = tid & 63;
  const int g = lane >> 4, c = lane & 15;
  const int wr = wave >> 1, wc = wave & 1;
  const int m0 = blockIdx.y * 128, n0 = blockIdx.x * 128;
  const int srow = lane >> 3;
  const int sch  = ((lane & 7) ^ srow) * 8;

  f32x4 acc[4][4] = {};
  const int nkt = K >> 6;

#define GSTAGE(buf, kt) do {                                                     \
    const int k0s = (kt) * 64;                                                   \
    _Pragma("unroll")                                                            \
    for (int i_ = 0; i_ < 4; ++i_) {                                             \
      const int chunk = i_ * 4 + wave;                                           \
      GLD16(A + (size_t)(m0 + chunk * 8 + srow) * K + k0s + sch,                 \
            &lA[buf][0] + chunk * 512);                                          \
      GLD16(Bt + (size_t)(n0 + chunk * 8 + srow) * K + k0s + sch,                \
            &lB[buf][0] + chunk * 512);                                          \
    }                                                                            \
  } while (0)

  GSTAGE(0, 0);
  GSTAGE(1, 1);
  VMCNT(8);
  __syncthreads();

  int p = 0;
  for (int kt = 0; kt < nkt; ++kt) {
    const int x7 = c & 7;
    const lds_cp a0 = (lds_cp)&lA[p][0] + (wr * 64 + c) * 64 + (g ^ x7) * 8;
    const lds_cp b0 = (lds_cp)&lB[p][0] + (wc * 64 + c) * 64 + (g ^ x7) * 8;
    const lds_cp a1 = (lds_cp)&lA[p][0] + (wr * 64 + c) * 64 + ((g ^ x7) ^ 4) * 8;
    const lds_cp b1 = (lds_cp)&lB[p][0] + (wc * 64 + c) * 64 + ((g ^ x7) ^ 4) * 8;
    u32x4 af0[4], bf0[4], af1[4], bf1[4];
    DSR128(af0[0], a0, "0");    DSR128(af0[1], a0, "2048");
    DSR128(af0[2], a0, "4096"); DSR128(af0[3], a0, "6144");
    DSR128(bf0[0], b0, "0");    DSR128(bf0[1], b0, "2048");
    DSR128(bf0[2], b0, "4096"); DSR128(bf0[3], b0, "6144");
    DSR128(af1[0], a1, "0");    DSR128(af1[1], a1, "2048");
    DSR128(af1[2], a1, "4096"); DSR128(af1[3], a1, "6144");
    DSR128(bf1[0], b1, "0");    DSR128(bf1[1], b1, "2048");
    DSR128(bf1[2], b1, "4096"); DSR128(bf1[3], b1, "6144");

    LGKM(8);
    __builtin_amdgcn_s_setprio(1);
#pragma unroll
    for (int mi = 0; mi < 4; ++mi)
#pragma unroll
      for (int ni = 0; ni < 4; ++ni)
        acc[mi][ni] = mfma16(__builtin_bit_cast(bf16x8, af0[mi]),
                             __builtin_bit_cast(bf16x8, bf0[ni]), acc[mi][ni]);
    __builtin_amdgcn_s_setprio(0);

    LGKM(0);
    __syncthreads();
    if (kt + 2 < nkt) GSTAGE(p, kt + 2);

    __builtin_amdgcn_s_setprio(1);
#pragma unroll
    for (int mi = 0; mi < 4; ++mi)
#pragma unroll
      for (int ni = 0; ni < 4; ++ni)
        acc[mi][ni] = mfma16(__builtin_bit_cast(bf16x8, af1[mi]),
                             __builtin_bit_cast(bf16x8, bf1[ni]), acc[mi][ni]);
    __builtin_amdgcn_s_setprio(0);

    if (kt + 2 < nkt) { VMCNT(8); } else { VMCNT(0); }
    __syncthreads();
    p ^= 1;
  }
#undef GSTAGE

#pragma unroll
  for (int mi = 0; mi < 4; ++mi)
#pragma unroll
    for (int ni = 0; ni < 4; ++ni) {
      const int col = n0 + wc * 64 + ni * 16 + c;
      float bv = bias[col];
      if (col < bias_scale_end) bv *= ATT_C;
#pragma unroll
      for (int r = 0; r < 4; ++r) {
        const int row = m0 + wr * 64 + mi * 16 + g * 4 + r;
        const float v = acc[mi][ni][r] + bv;
        if (OUT_F32)
          ((float*)Cout)[(size_t)row * N + col] = v;
        else
          ((unsigned short*)Cout)[(size_t)row * N + col] = f2bu(v);
      }
    }
}

// ---------------- causal flash attention (r9 exact) ----------------
__global__ __launch_bounds__(256) void k_attn(const unsigned short* __restrict__ qkv,
                                              unsigned short* __restrict__ y) {
  __shared__ __attribute__((aligned(16))) unsigned short lK[2][4096];
  __shared__ __attribute__((aligned(16))) unsigned short lV[2][4096];

  const int tid = threadIdx.x, wave = tid >> 6, lane = tid & 63;
  const int g = lane >> 4, c = lane & 15;
  const int id = (int)blockIdx.x;
  const int xcd = id & 7, slot = id >> 3;
  const int bh = xcd + 8 * (slot & 7);   // bh%8 == xcd -> per-XCD K/V residency
  const int pr = slot >> 3;              // 0..7 pair index
  const int b = bh >> 4, hc = bh & 15;
  const size_t rb = (size_t)b * SS;

  const int kRow = lane >> 3;
  const int kCh  = ((lane & 7) ^ kRow) * 8;
  const int vRow = 4 * ((lane >> 5) & 1) + ((lane >> 1) & 3);
  const int vDim = 16 * ((lane >> 3) & 3) + (lane & 1) * 8;

#define STAGE(buf, kb) do {                                                        \
    const int k0s = (kb) * 64;                                                     \
    const int g16 = wave * 16;                                                     \
    GLD16(qkv + (rb + k0s + g16 + kRow) * 3072 + 1024 + hc * 64 + kCh,             \
          &lK[buf][0] + g16 * 64);                                                 \
    GLD16(qkv + (rb + k0s + g16 + 8 + kRow) * 3072 + 1024 + hc * 64 + kCh,         \
          &lK[buf][0] + (g16 + 8) * 64);                                           \
    GLD16(qkv + (rb + k0s + g16 + vRow) * 3072 + 2048 + hc * 64 + vDim,            \
          &lV[buf][0] + g16 * 64);                                                 \
    GLD16(qkv + (rb + k0s + g16 + 8 + vRow) * 3072 + 2048 + hc * 64 + vDim,        \
          &lV[buf][0] + (g16 + 8) * 64);                                           \
  } while (0)

#define TRRD(dst, OFFLIT) \
  asm volatile("ds_read_b64_tr_b16 %0, %1 offset:" OFFLIT : "=v"(dst) : "v"(vp))

  bf16x8 onesf;
  {
    u16x8 t;
#pragma unroll
    for (int j = 0; j < 8; ++j) t[j] = 0x3F80;  // bf16 1.0
    onesf = __builtin_bit_cast(bf16x8, t);
  }

  auto run_qtile = [&](int qt) {
    const int qw = qt * 128 + wave * 32;

    bf16x8 qf[2][2];
#pragma unroll
    for (int m = 0; m < 2; ++m)
#pragma unroll
      for (int kh = 0; kh < 2; ++kh)
        qf[m][kh] = *(const bf16x8*)(qkv + (rb + qw + m * 16 + c) * 3072 + hc * 64 + kh * 32 + g * 8);

    float mrun[2] = {-INFINITY, -INFINITY};
    f32x4 lsum[2] = {};
    f32x4 o[2][4] = {};
    const int nkb = 2 * qt + 2;

    auto compute = [&](int buf, int kb) {
      const int k0 = kb * 64;
      if (k0 > qw + 31) return;

      const lds_cp kbase = (lds_cp)&lK[buf][0];
      const lds_cp kp0 = kbase + c * 64 + ((g ^ (c & 7))) * 8;
      const lds_cp kp1 = kbase + c * 64 + (((4 + g) ^ (c & 7))) * 8;
      u32x4 kr[8];
      DSR128(kr[0], kp0, "0");    DSR128(kr[1], kp0, "2048");
      DSR128(kr[2], kp0, "4096"); DSR128(kr[3], kp0, "6144");
      DSR128(kr[4], kp1, "0");    DSR128(kr[5], kp1, "2048");
      DSR128(kr[6], kp1, "4096"); DSR128(kr[7], kp1, "6144");
      const lds_cp vp = (lds_cp)&lV[buf][0] + (lane >> 4) * 256 + (lane & 15) * 4;
      u32x2 t0[8];
      TRRD(t0[0], "0");   TRRD(t0[1], "2048");
      TRRD(t0[2], "128"); TRRD(t0[3], "2176");
      TRRD(t0[4], "256"); TRRD(t0[5], "2304");
      TRRD(t0[6], "384"); TRRD(t0[7], "2432");
      LGKM(8);

      f32x4 s[2][4];
      __builtin_amdgcn_s_setprio(1);
#pragma unroll
      for (int kf = 0; kf < 4; ++kf) {
        const bf16x8 ka = __builtin_bit_cast(bf16x8, kr[kf]);
        const bf16x8 kb2 = __builtin_bit_cast(bf16x8, kr[4 + kf]);
#pragma unroll
        for (int m = 0; m < 2; ++m) {
          f32x4 a = {};
          a = mfma16(ka, qf[m][0], a);
          a = mfma16(kb2, qf[m][1], a);
          s[m][kf] = a;
        }
      }
      __builtin_amdgcn_s_setprio(0);

      u32x2 t1[8];
      TRRD(t1[0], "4096"); TRRD(t1[1], "6144");
      TRRD(t1[2], "4224"); TRRD(t1[3], "6272");
      TRRD(t1[4], "4352"); TRRD(t1[5], "6400");
      TRRD(t1[6], "4480"); TRRD(t1[7], "6528");

#pragma unroll
      for (int m = 0; m < 2; ++m)
#pragma unroll
        for (int kf = 0; kf < 4; ++kf)
          if (k0 + kf * 16 + 15 > qw + m * 16) {
#pragma unroll
            for (int r = 0; r < 4; ++r)
              if (k0 + kf * 16 + 4 * g + r > qw + m * 16 + c) s[m][kf][r] = -INFINITY;
          }

#pragma unroll
      for (int m = 0; m < 2; ++m) {
        float a0 = fmaxf(fmaxf(s[m][0][0], s[m][0][1]), s[m][0][2]);
        float a1 = fmaxf(fmaxf(s[m][0][3], s[m][1][0]), s[m][1][1]);
        float a2 = fmaxf(fmaxf(s[m][1][2], s[m][1][3]), s[m][2][0]);
        float a3 = fmaxf(fmaxf(s[m][2][1], s[m][2][2]), s[m][2][3]);
        float a4 = fmaxf(fmaxf(s[m][3][0], s[m][3][1]), s[m][3][2]);
        float b0 = fmaxf(fmaxf(a0, a1), a2);
        float b1 = fmaxf(fmaxf(a3, a4), s[m][3][3]);
        float tmax = fmaxf(b0, b1);
        tmax = fmaxf(tmax, __shfl_xor(tmax, 16));
        tmax = fmaxf(tmax, __shfl_xor(tmax, 32));
        const float mold = mrun[m];
        float mt;
        if (__all(tmax - mold <= 8.f)) {
          mt = mold;
        } else {
          mt = fmaxf(mold, tmax);
          const float alpha = __builtin_amdgcn_exp2f(mold - mt);
          mrun[m] = mt;
#pragma unroll
          for (int r = 0; r < 4; ++r) {
            const float ao = __shfl(alpha, (lane & 48) + ((lane & 48) >> 2) + r);
            lsum[m][r] *= ao;
#pragma unroll
            for (int dc = 0; dc < 4; ++dc) o[m][dc][r] *= ao;
          }
        }
#pragma unroll
        for (int kf = 0; kf < 4; ++kf)
#pragma unroll
          for (int r = 0; r < 4; ++r)
            s[m][kf][r] = __builtin_amdgcn_exp2f(s[m][kf][r] - mt);
      }

      bf16x8 pa[2][2];
#pragma unroll
      for (int m = 0; m < 2; ++m)
#pragma unroll
        for (int kh = 0; kh < 2; ++kh) {
          u16x8 t;
#pragma unroll
          for (int j = 0; j < 4; ++j) {
            t[j]     = f2bu(s[m][2 * kh][j]);
            t[4 + j] = f2bu(s[m][2 * kh + 1][j]);
          }
          pa[m][kh] = __builtin_bit_cast(bf16x8, t);
        }

      LGKM(8);
      __builtin_amdgcn_s_setprio(1);
#pragma unroll
      for (int m = 0; m < 2; ++m) {
        lsum[m] = mfma16(pa[m][0], onesf, lsum[m]);
        lsum[m] = mfma16(pa[m][1], onesf, lsum[m]);
      }
#pragma unroll
      for (int dc = 0; dc < 4; ++dc) {
        u32x4 vv = {t0[2 * dc][0], t0[2 * dc][1], t0[2 * dc + 1][0], t0[2 * dc + 1][1]};
        const bf16x8 vf = __builtin_bit_cast(bf16x8, vv);
#pragma unroll
        for (int m = 0; m < 2; ++m) o[m][dc] = mfma16(pa[m][0], vf, o[m][dc]);
      }
      __builtin_amdgcn_s_setprio(0);

      LGKM(0);
      __builtin_amdgcn_s_setprio(1);
#pragma unroll
      for (int dc = 0; dc < 4; ++dc) {
        u32x4 vv = {t1[2 * dc][0], t1[2 * dc][1], t1[2 * dc + 1][0], t1[2 * dc + 1][1]};
        const bf16x8 vf = __builtin_bit_cast(bf16x8, vv);
#pragma unroll
        for (int m = 0; m < 2; ++m) o[m][dc] = mfma16(pa[m][1], vf, o[m][dc]);
      }
      __builtin_amdgcn_s_setprio(0);
    };

    __syncthreads();
    STAGE(0, 0);
    asm volatile("s_waitcnt vmcnt(0)" ::: "memory");
    __syncthreads();
    int cur = 0;
    for (int kb = 0; kb < nkb - 1; ++kb) {
      STAGE(cur ^ 1, kb + 1);
      compute(cur, kb);
      asm volatile("s_waitcnt vmcnt(0)" ::: "memory");
      __syncthreads();
      cur ^= 1;
    }
    compute(cur, nkb - 1);

#pragma unroll
    for (int m = 0; m < 2; ++m)
#pragma unroll
      for (int r = 0; r < 4; ++r) {
        const float inv = __builtin_amdgcn_rcpf(lsum[m][r]);
        const int q = qw + m * 16 + 4 * g + r;
#pragma unroll
        for (int dc = 0; dc < 4; ++dc)
          y[(rb + q) * 1024 + hc * 64 + dc * 16 + c] = f2bu(o[m][dc][r] * inv);
      }
  };

  run_qtile(15 - pr);
  run_qtile(pr);
#undef STAGE
#undef TRRD
}

// ---------------- launch ----------------
extern "C" void kernel_launch(void* const* d_in, const int* in_sizes, int n_in,
                              void* d_out, int out_size, void* d_ws, size_t ws_size,
                              hipStream_t stream) {
  (void)in_sizes; (void)n_in; (void)out_size; (void)ws_size;
  const float* x     = (const float*)d_in[0];
  const float* w_qkv = (const float*)d_in[1];
  const float* b_qkv = (const float*)d_in[2];
  const float* w_out = (const float*)d_in[3];
  const float* b_out = (const float*)d_in[4];
  float* out = (float*)d_out;

  char* ws = (char*)d_ws;
  unsigned short* x_bf  = (unsigned short*)(ws);                        // 16 MB (reused for y)
  unsigned short* wqkvT = (unsigned short*)(ws + (size_t)16 * 1048576); // 6 MB
  unsigned short* woutT = (unsigned short*)(ws + (size_t)22 * 1048576); // 2 MB
  unsigned short* qkv   = (unsigned short*)(ws + (size_t)24 * 1048576); // 48 MB -> total 72 MB

  // prep (Q weight columns pre-scaled by ATT_C)
  k_cast_bf16<<<dim3((MM * DD) / (256 * 8)), 256, 0, stream>>>(x, x_bf, MM * DD);
  k_transpose_bf16<<<dim3(3 * DD / 32, DD / 32), 256, 0, stream>>>(w_qkv, wqkvT, DD, 3 * DD,
                                                                   ATT_C, DD);
  k_transpose_bf16<<<dim3(DD / 32, DD / 32), 256, 0, stream>>>(w_out, woutT, DD, DD, 1.f, 0);

  // QKV projection: [8192,3072] bf16 — 256² 8-phase pipeline, grid 12x32 = 384
  k_gemm8p<<<dim3(3 * DD / 256, MM / 256), 512, 0, stream>>>(
      x_bf, wqkvT, b_qkv, qkv, MM, 3 * DD, DD, DD);

  // causal attention -> y (bf16, reuses x_bf region); grid 512, XCD-binding decode
  k_attn<<<dim3(512), 256, 0, stream>>>(qkv, x_bf);

  // output projection: fp32 out (r9's 128² pipeline)
  k_gemm_bt<1><<<dim3(DD / 128, MM / 128), 256, 0, stream>>>(
      x_bf, woutT, b_out, out, MM, DD, DD, 0);
}

// Round 15
// 167.953 us; speedup vs baseline: 1.2348x; 1.0563x over previous
//
#include <hip/hip_runtime.h>
#include <hip/hip_bf16.h>
#include <cmath>
#include <cstdint>

// Problem dims (fixed by the reference)
#define BB 4
#define SS 2048
#define DD 1024
#define HH 16
#define MM (BB * SS)   // 8192 tokens

// softmax scale folded into Q weight columns: (1/sqrt(64)) * log2(e)
#define ATT_C 0.18033688011112042f

typedef __attribute__((ext_vector_type(8))) __bf16 bf16x8;
typedef __attribute__((ext_vector_type(4))) float f32x4;
typedef __attribute__((ext_vector_type(8))) float f32x8;
typedef __attribute__((ext_vector_type(8))) unsigned short u16x8;
typedef __attribute__((ext_vector_type(2))) unsigned int u32x2;
typedef __attribute__((ext_vector_type(4))) unsigned int u32x4;

typedef const __attribute__((address_space(3))) unsigned short* lds_cp;

__device__ __forceinline__ unsigned short f2bu(float f) {
  __hip_bfloat16 h = __float2bfloat16(f);
  return __builtin_bit_cast(unsigned short, h);
}

__device__ __forceinline__ f32x4 mfma16(bf16x8 a, bf16x8 b, f32x4 c) {
  return __builtin_amdgcn_mfma_f32_16x16x32_bf16(a, b, c, 0, 0, 0);
}

#define GLD16(gp, lp) __builtin_amdgcn_global_load_lds(                     \
    (const __attribute__((address_space(1))) void*)(gp),                    \
    (__attribute__((address_space(3))) void*)(lp), 16, 0, 0)

#define DSR128(dst, ptr, OFFLIT) \
  asm volatile("ds_read_b128 %0, %1 offset:" OFFLIT : "=v"(dst) : "v"(ptr))
#define LGKM(N) do { asm volatile("s_waitcnt lgkmcnt(" #N ")" ::: "memory"); \
                     __builtin_amdgcn_sched_barrier(0); } while (0)
#define VMCNT(N) do { asm volatile("s_waitcnt vmcnt(" #N ")" ::: "memory"); \
                      __builtin_amdgcn_sched_barrier(0); } while (0)

// ---------------- fused prep: cast x -> bf16; transpose+cast w_qkv, w_out ----------
// Three independent paths decoded from blockIdx.x (disjoint tensors):
//   [0, 4096)        : x [8192x1024] fp32 -> bf16 (vectorized, 2048 elem/block)
//   [4096, 7168)     : w_qkv [1024x3072] -> wqkvT [3072x1024] bf16, Q cols scaled ATT_C
//   [7168, 8192)     : w_out [1024x1024] -> woutT [1024x1024] bf16
__global__ __launch_bounds__(256) void k_prep(const float* __restrict__ x,
                                              unsigned short* __restrict__ x_bf,
                                              const float* __restrict__ w_qkv,
                                              unsigned short* __restrict__ wqkvT,
                                              const float* __restrict__ w_out,
                                              unsigned short* __restrict__ woutT) {
  const int bid = (int)blockIdx.x;
  if (bid < 4096) {  // cast path
    const int i = (bid * 256 + (int)threadIdx.x) * 8;
    f32x8 v = *(const f32x8*)(x + i);
    u16x8 o;
#pragma unroll
    for (int j = 0; j < 8; ++j) o[j] = f2bu(v[j]);
    *(u16x8*)(x_bf + i) = o;
    return;
  }
  // transpose paths (block-uniform selection; __syncthreads only on this side)
  __shared__ float tile[32][33];
  const float* in;
  unsigned short* out;
  int C, bx, by;
  float scale;
  int scale_end;
  if (bid < 7168) {
    const int t = bid - 4096;
    bx = t % 96; by = t / 96;
    in = w_qkv; out = wqkvT; C = 3 * DD; scale = ATT_C; scale_end = DD;
  } else {
    const int t = bid - 7168;
    bx = t & 31; by = t >> 5;
    in = w_out; out = woutT; C = DD; scale = 1.f; scale_end = 0;
  }
  const int R = DD;
  const int c0 = bx * 32, r0 = by * 32;
  const int tx = threadIdx.x & 31, ty = threadIdx.x >> 5;  // ty 0..7
#pragma unroll
  for (int i = ty; i < 32; i += 8)
    tile[i][tx] = in[(size_t)(r0 + i) * C + c0 + tx];
  __syncthreads();
#pragma unroll
  for (int i = ty; i < 32; i += 8) {
    float v = tile[tx][i];
    if (c0 + i < scale_end) v *= scale;
    out[(size_t)(c0 + i) * R + r0 + tx] = f2bu(v);
  }
}

// ---------------- bf16 GEMM: 128x128 tile, 2-deep counted pipeline (r9 form) ----------
// C[M][N] = A[M][K] * Bt[N][K]^T + bias[N]  (bias cols < bias_scale_end scaled by ATT_C)
// LDS [row][64k], 16B-chunk XOR swizzle ch^(row&7), staged via pre-swizzled source.
template <int OUT_F32>
__global__ __launch_bounds__(256) void k_gemm_bt(const unsigned short* __restrict__ A,
                                                 const unsigned short* __restrict__ Bt,
                                                 const float* __restrict__ bias,
                                                 void* __restrict__ Cout,
                                                 int M, int N, int K, int bias_scale_end) {
  __shared__ __attribute__((aligned(16))) unsigned short lA[2][128 * 64];
  __shared__ __attribute__((aligned(16))) unsigned short lB[2][128 * 64];
  const int tid = threadIdx.x;
  const int wave = tid >> 6, lane = tid & 63;
  const int g = lane >> 4, c = lane & 15;
  const int wr = wave >> 1, wc = wave & 1;
  const int m0 = blockIdx.y * 128, n0 = blockIdx.x * 128;
  const int srow = lane >> 3;                  // 0..7 row within 8-row group
  const int sch  = ((lane & 7) ^ srow) * 8;    // XOR-pre-swizzled source k-chunk

  f32x4 acc[4][4] = {};
  const int nkt = K >> 6;

#define GSTAGE(buf, kt) do {                                                     \
    const int k0s = (kt) * 64;                                                   \
    _Pragma("unroll")                                                            \
    for (int i_ = 0; i_ < 4; ++i_) {                                             \
      const int chunk = i_ * 4 + wave;                                           \
      GLD16(A + (size_t)(m0 + chunk * 8 + srow) * K + k0s + sch,                 \
            &lA[buf][0] + chunk * 512);                                          \
      GLD16(Bt + (size_t)(n0 + chunk * 8 + srow) * K + k0s + sch,                \
            &lB[buf][0] + chunk * 512);                                          \
    }                                                                            \
  } while (0)

  GSTAGE(0, 0);
  GSTAGE(1, 1);
  VMCNT(8);  // tile 0 landed (tile 1's 8 loads still in flight)
  __syncthreads();

  int p = 0;
  for (int kt = 0; kt < nkt; ++kt) {
    const int x7 = c & 7;
    const lds_cp a0 = (lds_cp)&lA[p][0] + (wr * 64 + c) * 64 + (g ^ x7) * 8;
    const lds_cp b0 = (lds_cp)&lB[p][0] + (wc * 64 + c) * 64 + (g ^ x7) * 8;
    const lds_cp a1 = (lds_cp)&lA[p][0] + (wr * 64 + c) * 64 + ((g ^ x7) ^ 4) * 8;
    const lds_cp b1 = (lds_cp)&lB[p][0] + (wc * 64 + c) * 64 + ((g ^ x7) ^ 4) * 8;
    u32x4 af0[4], bf0[4], af1[4], bf1[4];
    DSR128(af0[0], a0, "0");    DSR128(af0[1], a0, "2048");
    DSR128(af0[2], a0, "4096"); DSR128(af0[3], a0, "6144");
    DSR128(bf0[0], b0, "0");    DSR128(bf0[1], b0, "2048");
    DSR128(bf0[2], b0, "4096"); DSR128(bf0[3], b0, "6144");
    DSR128(af1[0], a1, "0");    DSR128(af1[1], a1, "2048");
    DSR128(af1[2], a1, "4096"); DSR128(af1[3], a1, "6144");
    DSR128(bf1[0], b1, "0");    DSR128(bf1[1], b1, "2048");
    DSR128(bf1[2], b1, "4096"); DSR128(bf1[3], b1, "6144");

    LGKM(8);  // kk0 frags ready (kk1 reads in flight)
    __builtin_amdgcn_s_setprio(1);
#pragma unroll
    for (int mi = 0; mi < 4; ++mi)
#pragma unroll
      for (int ni = 0; ni < 4; ++ni)
        acc[mi][ni] = mfma16(__builtin_bit_cast(bf16x8, af0[mi]),
                             __builtin_bit_cast(bf16x8, bf0[ni]), acc[mi][ni]);
    __builtin_amdgcn_s_setprio(0);

    LGKM(0);          // all reads from buf p done
    __syncthreads();  // every wave consumed buf p -> safe to overwrite
    if (kt + 2 < nkt) GSTAGE(p, kt + 2);

    __builtin_amdgcn_s_setprio(1);
#pragma unroll
    for (int mi = 0; mi < 4; ++mi)
#pragma unroll
      for (int ni = 0; ni < 4; ++ni)
        acc[mi][ni] = mfma16(__builtin_bit_cast(bf16x8, af1[mi]),
                             __builtin_bit_cast(bf16x8, bf1[ni]), acc[mi][ni]);
    __builtin_amdgcn_s_setprio(0);

    if (kt + 2 < nkt) { VMCNT(8); } else { VMCNT(0); }  // tile kt+1 landed
    __syncthreads();
    p ^= 1;
  }
#undef GSTAGE

#pragma unroll
  for (int mi = 0; mi < 4; ++mi)
#pragma unroll
    for (int ni = 0; ni < 4; ++ni) {
      const int col = n0 + wc * 64 + ni * 16 + c;
      float bv = bias[col];
      if (col < bias_scale_end) bv *= ATT_C;
#pragma unroll
      for (int r = 0; r < 4; ++r) {
        const int row = m0 + wr * 64 + mi * 16 + g * 4 + r;
        const float v = acc[mi][ni][r] + bv;
        if (OUT_F32)
          ((float*)Cout)[(size_t)row * N + col] = v;
        else
          ((unsigned short*)Cout)[(size_t)row * N + col] = f2bu(v);
      }
    }
}

// ---------------- causal flash attention (r9 exact) ----------------
// qkv: [B*S][3072] bf16 (Q pre-scaled by ATT_C, K at 1024, V at 2048; head h at h*64)
// y:   [B*S][1024] bf16
// Block: 4 waves x 32 Q rows (m=2) = 128-row q-tile; TWO q-tiles (15-p, p) per block
// -> uniform 34 tile-steps. Grid 512 = 8 xcd x 8 bh x 8 pairs, XCD-binding decode:
// bh%8 == xcd -> per-XCD L2-resident K/V (8 bh x 512KB = 4MB per XCD L2).
// KVBLK=64, dbuf LDS (32KB) -> 2 blocks/CU.
// K LDS: row-major [64 keys][64 hd], 16B-chunk XOR swizzle ch^(row&7); staged coalesced.
// V LDS: tr-subtiles ordered (k4*4+dc)*128B (coalesced staging); tr-read base
//   (lane>>4)*512B + (lane&15)*8B. Row-sums of P via ones-MFMA.
__global__ __launch_bounds__(256) void k_attn(const unsigned short* __restrict__ qkv,
                                              unsigned short* __restrict__ y) {
  __shared__ __attribute__((aligned(16))) unsigned short lK[2][4096];
  __shared__ __attribute__((aligned(16))) unsigned short lV[2][4096];

  const int tid = threadIdx.x, wave = tid >> 6, lane = tid & 63;
  const int g = lane >> 4, c = lane & 15;
  const int id = (int)blockIdx.x;
  const int xcd = id & 7, slot = id >> 3;
  const int bh = xcd + 8 * (slot & 7);   // bh%8 == xcd -> per-XCD K/V residency
  const int pr = slot >> 3;              // 0..7 pair index
  const int b = bh >> 4, hc = bh & 15;
  const size_t rb = (size_t)b * SS;

  const int kRow = lane >> 3;
  const int kCh  = ((lane & 7) ^ kRow) * 8;
  const int vRow = 4 * ((lane >> 5) & 1) + ((lane >> 1) & 3);
  const int vDim = 16 * ((lane >> 3) & 3) + (lane & 1) * 8;

#define STAGE(buf, kb) do {                                                        \
    const int k0s = (kb) * 64;                                                     \
    const int g16 = wave * 16;                                                     \
    GLD16(qkv + (rb + k0s + g16 + kRow) * 3072 + 1024 + hc * 64 + kCh,             \
          &lK[buf][0] + g16 * 64);                                                 \
    GLD16(qkv + (rb + k0s + g16 + 8 + kRow) * 3072 + 1024 + hc * 64 + kCh,         \
          &lK[buf][0] + (g16 + 8) * 64);                                           \
    GLD16(qkv + (rb + k0s + g16 + vRow) * 3072 + 2048 + hc * 64 + vDim,            \
          &lV[buf][0] + g16 * 64);                                                 \
    GLD16(qkv + (rb + k0s + g16 + 8 + vRow) * 3072 + 2048 + hc * 64 + vDim,        \
          &lV[buf][0] + (g16 + 8) * 64);                                           \
  } while (0)

#define TRRD(dst, OFFLIT) \
  asm volatile("ds_read_b64_tr_b16 %0, %1 offset:" OFFLIT : "=v"(dst) : "v"(vp))

  bf16x8 onesf;
  {
    u16x8 t;
#pragma unroll
    for (int j = 0; j < 8; ++j) t[j] = 0x3F80;  // bf16 1.0
    onesf = __builtin_bit_cast(bf16x8, t);
  }

  auto run_qtile = [&](int qt) {
    const int qw = qt * 128 + wave * 32;

    bf16x8 qf[2][2];
#pragma unroll
    for (int m = 0; m < 2; ++m)
#pragma unroll
      for (int kh = 0; kh < 2; ++kh)
        qf[m][kh] = *(const bf16x8*)(qkv + (rb + qw + m * 16 + c) * 3072 + hc * 64 + kh * 32 + g * 8);

    float mrun[2] = {-INFINITY, -INFINITY};
    f32x4 lsum[2] = {};
    f32x4 o[2][4] = {};
    const int nkb = 2 * qt + 2;

    auto compute = [&](int buf, int kb) {
      const int k0 = kb * 64;
      if (k0 > qw + 31) return;  // fully masked for this wave (wave-uniform)

      const lds_cp kbase = (lds_cp)&lK[buf][0];
      const lds_cp kp0 = kbase + c * 64 + ((g ^ (c & 7))) * 8;
      const lds_cp kp1 = kbase + c * 64 + (((4 + g) ^ (c & 7))) * 8;
      u32x4 kr[8];
      DSR128(kr[0], kp0, "0");    DSR128(kr[1], kp0, "2048");
      DSR128(kr[2], kp0, "4096"); DSR128(kr[3], kp0, "6144");
      DSR128(kr[4], kp1, "0");    DSR128(kr[5], kp1, "2048");
      DSR128(kr[6], kp1, "4096"); DSR128(kr[7], kp1, "6144");
      const lds_cp vp = (lds_cp)&lV[buf][0] + (lane >> 4) * 256 + (lane & 15) * 4;
      u32x2 t0[8];
      TRRD(t0[0], "0");   TRRD(t0[1], "2048");
      TRRD(t0[2], "128"); TRRD(t0[3], "2176");
      TRRD(t0[4], "256"); TRRD(t0[5], "2304");
      TRRD(t0[6], "384"); TRRD(t0[7], "2432");
      LGKM(8);  // kr ready (t0 still in flight)

      f32x4 s[2][4];
      __builtin_amdgcn_s_setprio(1);
#pragma unroll
      for (int kf = 0; kf < 4; ++kf) {
        const bf16x8 ka = __builtin_bit_cast(bf16x8, kr[kf]);
        const bf16x8 kb2 = __builtin_bit_cast(bf16x8, kr[4 + kf]);
#pragma unroll
        for (int m = 0; m < 2; ++m) {
          f32x4 a = {};
          a = mfma16(ka, qf[m][0], a);
          a = mfma16(kb2, qf[m][1], a);
          s[m][kf] = a;
        }
      }
      __builtin_amdgcn_s_setprio(0);

      u32x2 t1[8];
      TRRD(t1[0], "4096"); TRRD(t1[1], "6144");
      TRRD(t1[2], "4224"); TRRD(t1[3], "6272");
      TRRD(t1[4], "4352"); TRRD(t1[5], "6400");
      TRRD(t1[6], "4480"); TRRD(t1[7], "6528");

#pragma unroll
      for (int m = 0; m < 2; ++m)
#pragma unroll
        for (int kf = 0; kf < 4; ++kf)
          if (k0 + kf * 16 + 15 > qw + m * 16) {
#pragma unroll
            for (int r = 0; r < 4; ++r)
              if (k0 + kf * 16 + 4 * g + r > qw + m * 16 + c) s[m][kf][r] = -INFINITY;
          }

#pragma unroll
      for (int m = 0; m < 2; ++m) {
        float a0 = fmaxf(fmaxf(s[m][0][0], s[m][0][1]), s[m][0][2]);
        float a1 = fmaxf(fmaxf(s[m][0][3], s[m][1][0]), s[m][1][1]);
        float a2 = fmaxf(fmaxf(s[m][1][2], s[m][1][3]), s[m][2][0]);
        float a3 = fmaxf(fmaxf(s[m][2][1], s[m][2][2]), s[m][2][3]);
        float a4 = fmaxf(fmaxf(s[m][3][0], s[m][3][1]), s[m][3][2]);
        float b0 = fmaxf(fmaxf(a0, a1), a2);
        float b1 = fmaxf(fmaxf(a3, a4), s[m][3][3]);
        float tmax = fmaxf(b0, b1);
        tmax = fmaxf(tmax, __shfl_xor(tmax, 16));
        tmax = fmaxf(tmax, __shfl_xor(tmax, 32));
        const float mold = mrun[m];
        float mt;
        if (__all(tmax - mold <= 8.f)) {
          mt = mold;
        } else {
          mt = fmaxf(mold, tmax);
          const float alpha = __builtin_amdgcn_exp2f(mold - mt);
          mrun[m] = mt;
#pragma unroll
          for (int r = 0; r < 4; ++r) {
            const float ao = __shfl(alpha, (lane & 48) + ((lane & 48) >> 2) + r);
            lsum[m][r] *= ao;
#pragma unroll
            for (int dc = 0; dc < 4; ++dc) o[m][dc][r] *= ao;
          }
        }
#pragma unroll
        for (int kf = 0; kf < 4; ++kf)
#pragma unroll
          for (int r = 0; r < 4; ++r)
            s[m][kf][r] = __builtin_amdgcn_exp2f(s[m][kf][r] - mt);
      }

      bf16x8 pa[2][2];
#pragma unroll
      for (int m = 0; m < 2; ++m)
#pragma unroll
        for (int kh = 0; kh < 2; ++kh) {
          u16x8 t;
#pragma unroll
          for (int j = 0; j < 4; ++j) {
            t[j]     = f2bu(s[m][2 * kh][j]);
            t[4 + j] = f2bu(s[m][2 * kh + 1][j]);
          }
          pa[m][kh] = __builtin_bit_cast(bf16x8, t);
        }

      LGKM(8);  // t0 ready (t1 younger, still in flight)
      __builtin_amdgcn_s_setprio(1);
#pragma unroll
      for (int m = 0; m < 2; ++m) {
        lsum[m] = mfma16(pa[m][0], onesf, lsum[m]);
        lsum[m] = mfma16(pa[m][1], onesf, lsum[m]);
      }
#pragma unroll
      for (int dc = 0; dc < 4; ++dc) {
        u32x4 vv = {t0[2 * dc][0], t0[2 * dc][1], t0[2 * dc + 1][0], t0[2 * dc + 1][1]};
        const bf16x8 vf = __builtin_bit_cast(bf16x8, vv);
#pragma unroll
        for (int m = 0; m < 2; ++m) o[m][dc] = mfma16(pa[m][0], vf, o[m][dc]);
      }
      __builtin_amdgcn_s_setprio(0);

      LGKM(0);  // t1 ready
      __builtin_amdgcn_s_setprio(1);
#pragma unroll
      for (int dc = 0; dc < 4; ++dc) {
        u32x4 vv = {t1[2 * dc][0], t1[2 * dc][1], t1[2 * dc + 1][0], t1[2 * dc + 1][1]};
        const bf16x8 vf = __builtin_bit_cast(bf16x8, vv);
#pragma unroll
        for (int m = 0; m < 2; ++m) o[m][dc] = mfma16(pa[m][1], vf, o[m][dc]);
      }
      __builtin_amdgcn_s_setprio(0);
    };

    __syncthreads();  // LDS handoff from previous q-tile
    STAGE(0, 0);
    asm volatile("s_waitcnt vmcnt(0)" ::: "memory");
    __syncthreads();
    int cur = 0;
    for (int kb = 0; kb < nkb - 1; ++kb) {
      STAGE(cur ^ 1, kb + 1);
      compute(cur, kb);
      asm volatile("s_waitcnt vmcnt(0)" ::: "memory");
      __syncthreads();
      cur ^= 1;
    }
    compute(cur, nkb - 1);

    // epilogue: normalize and store (lsum already in o's layout — no shfl)
#pragma unroll
    for (int m = 0; m < 2; ++m)
#pragma unroll
      for (int r = 0; r < 4; ++r) {
        const float inv = __builtin_amdgcn_rcpf(lsum[m][r]);
        const int q = qw + m * 16 + 4 * g + r;
#pragma unroll
        for (int dc = 0; dc < 4; ++dc)
          y[(rb + q) * 1024 + hc * 64 + dc * 16 + c] = f2bu(o[m][dc][r] * inv);
      }
  };

  // paired q-tiles: (15-p) then (p) -> uniform 34 tile-steps per block
  run_qtile(15 - pr);
  run_qtile(pr);
#undef STAGE
#undef TRRD
}

// ---------------- launch ----------------
extern "C" void kernel_launch(void* const* d_in, const int* in_sizes, int n_in,
                              void* d_out, int out_size, void* d_ws, size_t ws_size,
                              hipStream_t stream) {
  (void)in_sizes; (void)n_in; (void)out_size; (void)ws_size;
  const float* x     = (const float*)d_in[0];
  const float* w_qkv = (const float*)d_in[1];
  const float* b_qkv = (const float*)d_in[2];
  const float* w_out = (const float*)d_in[3];
  const float* b_out = (const float*)d_in[4];
  float* out = (float*)d_out;

  char* ws = (char*)d_ws;
  unsigned short* x_bf  = (unsigned short*)(ws);                        // 16 MB (reused for y)
  unsigned short* wqkvT = (unsigned short*)(ws + (size_t)16 * 1048576); // 6 MB
  unsigned short* woutT = (unsigned short*)(ws + (size_t)22 * 1048576); // 2 MB
  unsigned short* qkv   = (unsigned short*)(ws + (size_t)24 * 1048576); // 48 MB -> total 72 MB

  // fused prep: cast x + transpose w_qkv (Q cols pre-scaled) + transpose w_out
  k_prep<<<dim3(8192), 256, 0, stream>>>(x, x_bf, w_qkv, wqkvT, w_out, woutT);

  // QKV projection: [8192,3072] bf16 (r9's proven 128² pipeline)
  k_gemm_bt<0><<<dim3(3 * DD / 128, MM / 128), 256, 0, stream>>>(
      x_bf, wqkvT, b_qkv, qkv, MM, 3 * DD, DD, DD);

  // causal attention -> y (bf16, reuses x_bf region); grid 512, XCD-binding decode
  k_attn<<<dim3(512), 256, 0, stream>>>(qkv, x_bf);

  // output projection: fp32 out (r9's 128² pipeline)
  k_gemm_bt<1><<<dim3(DD / 128, MM / 128), 256, 0, stream>>>(
      x_bf, woutT, b_out, out, MM, DD, DD, 0);
}